// Round 8
// baseline (377.599 us; speedup 1.0000x reference)
//
#include <hip/hip_runtime.h>
#include <hip/hip_bf16.h>

#define AS1 __attribute__((address_space(1)))
#define AS3 __attribute__((address_space(3)))

typedef __attribute__((ext_vector_type(8))) short bf16x8;
typedef __attribute__((ext_vector_type(4))) float f32x4;

#define CSTRIDE 9216   // coeff row stride = O*(D+1)
#define KT2 8192       // GEMM K: polys T_1..T_8, k = (d-1)*1024 + i
#define NOUT 1024

__device__ __forceinline__ void gll16(const void* g, void* l) {
    __builtin_amdgcn_global_load_lds((const AS1 void*)g, (AS3 void*)l, 16, 0, 0);
}
static __device__ __forceinline__ unsigned short f2bf(float f) {
    union { __hip_bfloat16 h; unsigned short u; } cv;
    cv.h = __float2bfloat16(f);
    return cv.u;
}
static __device__ __forceinline__ float bf2f(unsigned short u) {
    union { float f; unsigned v; } c; c.v = (unsigned)u << 16; return c.f;
}
static __device__ __forceinline__ float fast_tanhf(float v) {
    float e = __expf(2.0f * v);
    return 1.0f - 2.0f / (e + 1.0f);
}

// ---------------------------------------------------------------------------
// Prep: cc (I=1024, O=1024, 9) f32 -> Wt[n][k] bf16, k=(d-1)*1024+i (d=1..8),
// PRE-SWIZZLED within each 64-chunk (Wt[n][e] = W[n][e ^ ((n&7)<<3)]) so a
// linear global_load_lds lands XOR-swizzled in LDS. Plus bias[o] = sum_i
// cc[i][o][0] (the T_0 term) via fp32 atomics.  (proven R4-R7)
// ---------------------------------------------------------------------------
__global__ void __launch_bounds__(256) prep_kernel(const float* __restrict__ cc,
                                                   unsigned short* __restrict__ Wt,
                                                   float* __restrict__ bias) {
    __shared__ unsigned short T[288 * 68];  // [f = nl*9 + d][il], pad 68
    const int t  = threadIdx.x;
    const int n0 = (blockIdx.x & 31) * 32;
    const int i0 = (blockIdx.x >> 5) * 64;

    for (int il = 0; il < 64; ++il) {
        const float* src = cc + (size_t)(i0 + il) * CSTRIDE + (size_t)n0 * 9;
        for (int f = t; f < 288; f += 256)
            T[f * 68 + il] = f2bf(src[f]);
    }
    __syncthreads();

#pragma unroll
    for (int it = 0; it < 16; ++it) {
        const int chunk = it * 16 + (t >> 4);
        const int nl = chunk >> 3;
        const int dd = chunk & 7;
        const int n  = n0 + nl;
        const int e0 = (t & 15) * 4;
        const int isrc = e0 ^ ((n & 7) << 3);
        ushort4 v = *(const ushort4*)&T[(nl * 9 + dd + 1) * 68 + isrc];
        *(ushort4*)(Wt + (size_t)n * KT2 + dd * 1024 + i0 + e0) = v;
    }

    if (t < 32) {
        float s = 0.f;
#pragma unroll 8
        for (int il = 0; il < 64; ++il) s += bf2f(T[(t * 9) * 68 + il]);
        atomicAdd(&bias[n0 + t], s);
    }
}

// ---------------------------------------------------------------------------
// Fused GEMM: out[8192][1024] = Cheby_{1..8}(tanh(x)) @ Wt^T + bias
// 128x128 tile, 512 threads = 8 waves (2 row-bands x 4 col-bands; wave tile
// 64x32). R8 change vs R7: A and B both LDS DOUBLE-BUFFERED -> ONE
// __syncthreads per step instead of two. Step s: issue B-DMA(s+1)->nxt,
// ds_read frags(s)<-cur, generate A(s+1)->nxt, MFMA(s), barrier. MFMA(s)
// has no dependence on this step's writes, so the compiler interleaves the
// MFMA burst with gen VALU and hides frag lgkm latency under gen (the
// overlap the 2-barrier structure forbids). Full-drain barriers only —
// no counted vmcnt (R2/R4 lesson); the DMA drain hides in the ~full-step
// window between issue and barrier. No wrap prefetch at the last step
// (no dead loads -> no DCE trap, R3 lesson).
// ---------------------------------------------------------------------------
__global__ void __launch_bounds__(512, 4)
cheby_gemm(const float* __restrict__ x, const unsigned short* __restrict__ Wt,
           const float* __restrict__ bias, float* __restrict__ out) {
    __shared__ unsigned short Asub[2][128 * 64];   // 2 x 16 KB, swizzled
    __shared__ unsigned short Bsub[2][128 * 64];   // 2 x 16 KB, swizzled

    const int id   = blockIdx.x;       // 512 blocks
    const int bcol = (id & 7) * 128;   // col strip fixed per XCD
    const int brow = (id >> 3) * 128;
    const int t    = threadIdx.x;
    const int lane = t & 63;
    const int w    = t >> 6;           // 0..7
    const int wr   = (w >> 2) * 64;    // wave row offset (2 row-bands)
    const int wc   = (w & 3) * 32;     // wave col offset (4 col-bands)
    const int l15  = lane & 15;
    const int lhi  = lane >> 4;

    const int gi0 = (t & 15) * 4;   // gen: i-quad
    const int gr  = t >> 4;         // gen: base row 0..31, covers gr+32p, p<4
    const int bl3 = (lane >> 3);    // B staging: row-in-8
    const int bp8 = (lane & 7) * 8; // B staging: elem offset (16 B)

    char* const Abase = (char*)&Asub[0][0];
    char* const Bbase = (char*)&Bsub[0][0];

    unsigned awoff[4];
#pragma unroll
    for (int p = 0; p < 4; ++p) {
        const int r = gr + 32 * p;
        awoff[p] = r * 128 + ((gi0 * 2) ^ ((r & 7) << 4));
    }

    f32x4 acc[4][2] = {};
    float x2[4][4], Tp[4][4], Tpp[4][4];

    // ---- prologue: B(0) DMA + A(0) gen (tanh ic=0, T_1) into buffer 0 ----
#pragma unroll
    for (int c = 0; c < 2; ++c) {
        const int n_loc = w * 16 + c * 8;
        gll16(Wt + (size_t)(bcol + n_loc + bl3) * KT2 + bp8,
              Bbase + n_loc * 128);
    }
#pragma unroll
    for (int p = 0; p < 4; ++p) {
        const float4 v = *(const float4*)(x + (size_t)(brow + gr + 32 * p) * 1024 + gi0);
        ushort4 pk; unsigned short* pks = (unsigned short*)&pk;
#pragma unroll
        for (int j = 0; j < 4; ++j) {
            x2[p][j] = 2.0f * fast_tanhf((&v.x)[j]);
            const float c = 0.5f * x2[p][j];
            Tp[p][j] = c; Tpp[p][j] = 1.0f;
            pks[j] = f2bf(c);
        }
        *(ushort4*)(Abase + awoff[p]) = pk;
    }
    __syncthreads();

#pragma unroll 1
    for (int ic = 0; ic < 16; ++ic) {
#pragma unroll
        for (int dd = 0; dd < 8; ++dd) {
            const int s    = ic * 8 + dd;
            const int curo = (s & 1) << 14;      // byte offset of current buf
            const int nxto = curo ^ 16384;
            const bool pre = (s != 127);
            const int ddn  = (dd + 1) & 7;
            const int icn  = (dd == 7) ? (ic + 1) : ic;

            // (1) issue B(s+1) DMA into the other buffer
            if (pre) {
                const int kbn = ddn * 1024 + icn * 64;
#pragma unroll
                for (int c = 0; c < 2; ++c) {
                    const int n_loc = w * 16 + c * 8;
                    gll16(Wt + (size_t)(bcol + n_loc + bl3) * KT2 + kbn + bp8,
                          Bbase + nxto + n_loc * 128);
                }
            }

            // (2) frag reads for step s from the current buffer
            bf16x8 af[2][4], bfr[2][2];
#pragma unroll
            for (int ks = 0; ks < 2; ++ks) {
#pragma unroll
                for (int mf = 0; mf < 4; ++mf) {
                    const int row = wr + mf * 16 + l15;
                    af[ks][mf] = *(const bf16x8*)(Abase + curo + row * 128 +
                                  ((ks * 64 + lhi * 16) ^ ((row & 7) << 4)));
                }
#pragma unroll
                for (int nf = 0; nf < 2; ++nf) {
                    const int n = wc + nf * 16 + l15;
                    bfr[ks][nf] = *(const bf16x8*)(Bbase + curo + n * 128 +
                                  ((ks * 64 + lhi * 16) ^ ((n & 7) << 4)));
                }
            }

            // (3) generate A(s+1) = T_{ddn+1} into the other buffer
            if (pre) {
                if (ddn == 0) {
#pragma unroll
                    for (int p = 0; p < 4; ++p) {
                        const float4 v = *(const float4*)(x +
                            (size_t)(brow + gr + 32 * p) * 1024 + icn * 64 + gi0);
                        ushort4 pk; unsigned short* pks = (unsigned short*)&pk;
#pragma unroll
                        for (int j = 0; j < 4; ++j) {
                            x2[p][j] = 2.0f * fast_tanhf((&v.x)[j]);
                            const float c = 0.5f * x2[p][j];
                            Tp[p][j] = c; Tpp[p][j] = 1.0f;
                            pks[j] = f2bf(c);
                        }
                        *(ushort4*)(Abase + nxto + awoff[p]) = pk;
                    }
                } else {
#pragma unroll
                    for (int p = 0; p < 4; ++p) {
                        ushort4 pk; unsigned short* pks = (unsigned short*)&pk;
#pragma unroll
                        for (int j = 0; j < 4; ++j) {
                            const float c = __builtin_fmaf(x2[p][j], Tp[p][j], -Tpp[p][j]);
                            Tpp[p][j] = Tp[p][j]; Tp[p][j] = c;
                            pks[j] = f2bf(c);
                        }
                        *(ushort4*)(Abase + nxto + awoff[p]) = pk;
                    }
                }
            }

            // (4) MFMA(s) — depends only on buf[cur]; overlaps gen above
#pragma unroll
            for (int ks = 0; ks < 2; ++ks)
#pragma unroll
                for (int mf = 0; mf < 4; ++mf)
#pragma unroll
                    for (int nf = 0; nf < 2; ++nf)
                        acc[mf][nf] = __builtin_amdgcn_mfma_f32_16x16x32_bf16(
                            af[ks][mf], bfr[ks][nf], acc[mf][nf], 0, 0, 0);

            // (5) single barrier: drains DMA + gen writes + frag reads
            __syncthreads();
        }
    }

    // epilogue: C/D layout col = lane&15, row = (lane>>4)*4 + reg; + bias
    float bv[2];
#pragma unroll
    for (int nf = 0; nf < 2; ++nf) bv[nf] = bias[bcol + wc + nf * 16 + l15];
#pragma unroll
    for (int mf = 0; mf < 4; ++mf)
#pragma unroll
        for (int nf = 0; nf < 2; ++nf)
#pragma unroll
            for (int ri = 0; ri < 4; ++ri) {
                const int orow = brow + wr + mf * 16 + lhi * 4 + ri;
                const int ocol = bcol + wc + nf * 16 + l15;
                out[(size_t)orow * NOUT + ocol] = acc[mf][nf][ri] + bv[nf];
            }
}

// ---------------------------------------------------------------------------
// Fallback (ws too small): correct but slow fp32 path.
// ---------------------------------------------------------------------------
__global__ void __launch_bounds__(256) naive_kernel(const float* __restrict__ x,
                                                    const float* __restrict__ cc,
                                                    float* __restrict__ out) {
    __shared__ float xs[1024];
    const int b = blockIdx.x;
    const int t = threadIdx.x;
#pragma unroll
    for (int j = 0; j < 4; ++j)
        xs[t * 4 + j] = fast_tanhf(x[(size_t)b * 1024 + t * 4 + j]);
    __syncthreads();

    const int o = t * 4;
    float a0 = 0.f, a1 = 0.f, a2 = 0.f, a3 = 0.f;
    for (int i = 0; i < 1024; ++i) {
        const float* cp = cc + (size_t)i * CSTRIDE + (size_t)o * 9;
        const float xv = xs[i];
        float tpp = 1.0f, tp = xv;
        a0 += cp[0];  a1 += cp[9];  a2 += cp[18];  a3 += cp[27];
        a0 += xv * cp[1]; a1 += xv * cp[10]; a2 += xv * cp[19]; a3 += xv * cp[28];
#pragma unroll
        for (int d = 2; d <= 8; ++d) {
            const float cur = 2.0f * xv * tp - tpp;
            tpp = tp; tp = cur;
            a0 += cur * cp[d];      a1 += cur * cp[9 + d];
            a2 += cur * cp[18 + d]; a3 += cur * cp[27 + d];
        }
    }
    float* op = out + (size_t)b * NOUT + o;
    op[0] = a0; op[1] = a1; op[2] = a2; op[3] = a3;
}

extern "C" void kernel_launch(void* const* d_in, const int* in_sizes, int n_in,
                              void* d_out, int out_size, void* d_ws, size_t ws_size,
                              hipStream_t stream) {
    const float* x  = (const float*)d_in[0];
    const float* cc = (const float*)d_in[1];
    float* out = (float*)d_out;

    const size_t wt_bytes = (size_t)KT2 * 1024 * sizeof(unsigned short);  // 16 MiB
    const size_t need = wt_bytes + 1024 * sizeof(float);
    if (ws_size >= need) {
        unsigned short* Wt = (unsigned short*)d_ws;
        float* bias = (float*)((char*)d_ws + wt_bytes);
        hipMemsetAsync(bias, 0, 1024 * sizeof(float), stream);
        prep_kernel<<<512, 256, 0, stream>>>(cc, Wt, bias);
        cheby_gemm<<<512, 512, 0, stream>>>(x, Wt, bias, out);
    } else {
        naive_kernel<<<8192, 256, 0, stream>>>(x, cc, out);
    }
}

// Round 9
// 284.191 us; speedup vs baseline: 1.3287x; 1.3287x over previous
//
#include <hip/hip_runtime.h>
#include <hip/hip_bf16.h>

#define AS1 __attribute__((address_space(1)))
#define AS3 __attribute__((address_space(3)))

typedef __attribute__((ext_vector_type(8))) short bf16x8;
typedef __attribute__((ext_vector_type(4))) float f32x4;

#define CSTRIDE 9216   // coeff row stride = O*(D+1)
#define KT2 8192       // GEMM K: polys T_1..T_8, k' = ic*512 + dd*64 + e
#define NOUT 1024

__device__ __forceinline__ void gll16(const void* g, void* l) {
    __builtin_amdgcn_global_load_lds((const AS1 void*)g, (AS3 void*)l, 16, 0, 0);
}
static __device__ __forceinline__ unsigned short f2bf(float f) {
    union { __hip_bfloat16 h; unsigned short u; } cv;
    cv.h = __float2bfloat16(f);
    return cv.u;
}
static __device__ __forceinline__ float bf2f(unsigned short u) {
    union { float f; unsigned v; } c; c.v = (unsigned)u << 16; return c.f;
}
static __device__ __forceinline__ float fast_tanhf(float v) {
    float e = __expf(2.0f * v);
    return 1.0f - 2.0f / (e + 1.0f);
}

// ---------------------------------------------------------------------------
// Prep: cc (I=1024, O=1024, 9) f32 -> Wt[n][k'] bf16 with D-PAIR-MAJOR k':
// k' = ic*512 + dd*64 + e  (ic = i>>6, e = i&63, dd = degree-1, d=1..8),
// pre-swizzled within each 64-elem chunk (e ^ ((n&7)<<3)) so a linear
// global_load_lds lands XOR-swizzled in LDS. Each (ic, degree-pair) tile is
// 256 B contiguous per n-row -> BK=128 staging stays linear.
// Plus bias[o] = sum_i cc[i][o][0] (T_0 term) via fp32 atomics.
// ---------------------------------------------------------------------------
__global__ void __launch_bounds__(256) prep_kernel(const float* __restrict__ cc,
                                                   unsigned short* __restrict__ Wt,
                                                   float* __restrict__ bias) {
    __shared__ unsigned short T[288 * 68];  // [f = nl*9 + d][il], pad 68
    const int t  = threadIdx.x;
    const int n0 = (blockIdx.x & 31) * 32;
    const int i0 = (blockIdx.x >> 5) * 64;   // i-chunk base; ic = i0>>6

    for (int il = 0; il < 64; ++il) {
        const float* src = cc + (size_t)(i0 + il) * CSTRIDE + (size_t)n0 * 9;
        for (int f = t; f < 288; f += 256)
            T[f * 68 + il] = f2bf(src[f]);
    }
    __syncthreads();

#pragma unroll
    for (int it = 0; it < 16; ++it) {
        const int chunk = it * 16 + (t >> 4);
        const int nl = chunk >> 3;
        const int dd = chunk & 7;            // degree dd+1
        const int n  = n0 + nl;
        const int e0 = (t & 15) * 4;
        const int isrc = e0 ^ ((n & 7) << 3);
        ushort4 v = *(const ushort4*)&T[(nl * 9 + dd + 1) * 68 + isrc];
        *(ushort4*)(Wt + (size_t)n * KT2 + (i0 >> 6) * 512 + dd * 64 + e0) = v;
    }

    if (t < 32) {
        float s = 0.f;
#pragma unroll 8
        for (int il = 0; il < 64; ++il) s += bf2f(T[(t * 9) * 68 + il]);
        atomicAdd(&bias[n0 + t], s);
    }
}

// ---------------------------------------------------------------------------
// Fused GEMM: out[8192][1024] = Cheby_{1..8}(tanh(x)) @ Wt^T + bias
// R1's EXACT proven schedule (256 thr, 4 waves 64x64, single A/B LDS buffer,
// 2 full __syncthreads per step) with two deltas:
//   - K=8192: T_0 folded into bias (prep).
//   - BK=128: one step = (ic, degree-pair) -> 64 steps, 128 barriers
//     (vs R1's 288). Gen emits T_{2p+1},T_{2p+2} per step; recurrence
//     state unchanged (96 regs). LDS 32+32 KB, 2 blocks/CU, VGPR cap 256.
// No counted vmcnt, no reordered frag reads (R2/R4/R8 lessons).
// ---------------------------------------------------------------------------
__global__ void __launch_bounds__(256, 2)
cheby_gemm(const float* __restrict__ x, const unsigned short* __restrict__ Wt,
           const float* __restrict__ bias, float* __restrict__ out) {
    __shared__ unsigned short Asub[128 * 128];   // 32 KB, [row][kc] swizzled
    __shared__ unsigned short Bsub[128 * 128];   // 32 KB, [n][kc] swizzled

    const int id   = blockIdx.x;       // 512 blocks
    const int bcol = (id & 7) * 128;   // col strip fixed per XCD
    const int brow = (id >> 3) * 128;
    const int t    = threadIdx.x;
    const int lane = t & 63;
    const int w    = t >> 6;
    const int wr   = (w >> 1) * 64;
    const int wc   = (w & 1) * 64;
    const int l15  = lane & 15;
    const int lhi  = lane >> 4;

    const int gi0 = (t & 15) * 4;   // gen: i-quad
    const int gr  = t >> 4;         // gen: base row, covers gr+16p, p<8
    const int bn4 = lane >> 4;      // B staging: row-in-4 (0..3)
    const int be  = (lane & 15) * 8;// B staging: elem offset (16 B)

    // A write offsets: byte = r*256 + dloc*128 + ((gi0*2) ^ ((r&7)<<4))
    unsigned awoff[8];
#pragma unroll
    for (int p = 0; p < 8; ++p) {
        const int r = gr + 16 * p;
        awoff[p] = r * 256 + ((gi0 * 2) ^ ((r & 7) << 4));
    }

    f32x4 acc[4][4] = {};
    float x2[8][4], Tp[8][4], Tpp[8][4];

#pragma unroll 1
    for (int ic = 0; ic < 16; ++ic) {
#pragma unroll
        for (int dp = 0; dp < 4; ++dp) {       // degree pair: 2dp+1, 2dp+2
            __syncthreads();   // MFMA(s-1) reads done before overwriting LDS

            // stage B(s): 32 KB; per wave 8 calls x (64 lanes x 16 B).
            // Call c covers 4 n-rows (n_base = w*32 + c*4), 256 B/row.
            const int kb = ic * 512 + dp * 128;
#pragma unroll
            for (int c = 0; c < 8; ++c) {
                const int n_base = w * 32 + c * 4;
                gll16(Wt + (size_t)(bcol + n_base + bn4) * KT2 + kb + be,
                      (char*)Bsub + n_base * 256);
            }

            // generate A(s): degrees 2dp+1 and 2dp+2 (fp32 recurrence)
            if (dp == 0) {
#pragma unroll
                for (int p = 0; p < 8; ++p) {
                    const float4 v = *(const float4*)(x +
                        (size_t)(brow + gr + 16 * p) * 1024 + ic * 64 + gi0);
                    ushort4 pk1, pk2;
                    unsigned short* s1 = (unsigned short*)&pk1;
                    unsigned short* s2 = (unsigned short*)&pk2;
#pragma unroll
                    for (int j = 0; j < 4; ++j) {
                        x2[p][j] = 2.0f * fast_tanhf((&v.x)[j]);
                        const float t1 = 0.5f * x2[p][j];                       // T1
                        const float t2 = __builtin_fmaf(x2[p][j], t1, -1.0f);   // T2
                        Tpp[p][j] = t1; Tp[p][j] = t2;
                        s1[j] = f2bf(t1); s2[j] = f2bf(t2);
                    }
                    *(ushort4*)((char*)Asub + awoff[p]) = pk1;
                    *(ushort4*)((char*)Asub + awoff[p] + 128) = pk2;
                }
            } else {
#pragma unroll
                for (int p = 0; p < 8; ++p) {
                    ushort4 pk1, pk2;
                    unsigned short* s1 = (unsigned short*)&pk1;
                    unsigned short* s2 = (unsigned short*)&pk2;
#pragma unroll
                    for (int j = 0; j < 4; ++j) {
                        const float ta = __builtin_fmaf(x2[p][j], Tp[p][j], -Tpp[p][j]);
                        const float tb = __builtin_fmaf(x2[p][j], ta, -Tp[p][j]);
                        Tpp[p][j] = ta; Tp[p][j] = tb;
                        s1[j] = f2bf(ta); s2[j] = f2bf(tb);
                    }
                    *(ushort4*)((char*)Asub + awoff[p]) = pk1;
                    *(ushort4*)((char*)Asub + awoff[p] + 128) = pk2;
                }
            }

            __syncthreads();   // full drain: A written, B landed

            // MFMA phase: BK=128 -> 4 k-steps of 32
#pragma unroll
            for (int ks = 0; ks < 4; ++ks) {
                const int koff = (ks >> 1) * 128;          // degree chunk
                const int kin  = (ks & 1) * 64 + lhi * 16; // within-chunk byte
                bf16x8 af[4], bfr[4];
#pragma unroll
                for (int mf = 0; mf < 4; ++mf) {
                    const int row = wr + mf * 16 + l15;
                    af[mf] = *(const bf16x8*)((const char*)Asub + row * 256 +
                              koff + (kin ^ ((row & 7) << 4)));
                }
#pragma unroll
                for (int nf = 0; nf < 4; ++nf) {
                    const int n = wc + nf * 16 + l15;
                    bfr[nf] = *(const bf16x8*)((const char*)Bsub + n * 256 +
                              koff + (kin ^ ((n & 7) << 4)));
                }
#pragma unroll
                for (int mf = 0; mf < 4; ++mf)
#pragma unroll
                    for (int nf = 0; nf < 4; ++nf)
                        acc[mf][nf] = __builtin_amdgcn_mfma_f32_16x16x32_bf16(
                            af[mf], bfr[nf], acc[mf][nf], 0, 0, 0);
            }
        }
    }

    // epilogue: C/D layout col = lane&15, row = (lane>>4)*4 + reg; + bias
    float bv[4];
#pragma unroll
    for (int nf = 0; nf < 4; ++nf) bv[nf] = bias[bcol + wc + nf * 16 + l15];
#pragma unroll
    for (int mf = 0; mf < 4; ++mf)
#pragma unroll
        for (int nf = 0; nf < 4; ++nf)
#pragma unroll
            for (int ri = 0; ri < 4; ++ri) {
                const int orow = brow + wr + mf * 16 + lhi * 4 + ri;
                const int ocol = bcol + wc + nf * 16 + l15;
                out[(size_t)orow * NOUT + ocol] = acc[mf][nf][ri] + bv[nf];
            }
}

// ---------------------------------------------------------------------------
// Fallback (ws too small): correct but slow fp32 path.
// ---------------------------------------------------------------------------
__global__ void __launch_bounds__(256) naive_kernel(const float* __restrict__ x,
                                                    const float* __restrict__ cc,
                                                    float* __restrict__ out) {
    __shared__ float xs[1024];
    const int b = blockIdx.x;
    const int t = threadIdx.x;
#pragma unroll
    for (int j = 0; j < 4; ++j)
        xs[t * 4 + j] = fast_tanhf(x[(size_t)b * 1024 + t * 4 + j]);
    __syncthreads();

    const int o = t * 4;
    float a0 = 0.f, a1 = 0.f, a2 = 0.f, a3 = 0.f;
    for (int i = 0; i < 1024; ++i) {
        const float* cp = cc + (size_t)i * CSTRIDE + (size_t)o * 9;
        const float xv = xs[i];
        float tpp = 1.0f, tp = xv;
        a0 += cp[0];  a1 += cp[9];  a2 += cp[18];  a3 += cp[27];
        a0 += xv * cp[1]; a1 += xv * cp[10]; a2 += xv * cp[19]; a3 += xv * cp[28];
#pragma unroll
        for (int d = 2; d <= 8; ++d) {
            const float cur = 2.0f * xv * tp - tpp;
            tpp = tp; tp = cur;
            a0 += cur * cp[d];      a1 += cur * cp[9 + d];
            a2 += cur * cp[18 + d]; a3 += cur * cp[27 + d];
        }
    }
    float* op = out + (size_t)b * NOUT + o;
    op[0] = a0; op[1] = a1; op[2] = a2; op[3] = a3;
}

extern "C" void kernel_launch(void* const* d_in, const int* in_sizes, int n_in,
                              void* d_out, int out_size, void* d_ws, size_t ws_size,
                              hipStream_t stream) {
    const float* x  = (const float*)d_in[0];
    const float* cc = (const float*)d_in[1];
    float* out = (float*)d_out;

    const size_t wt_bytes = (size_t)KT2 * 1024 * sizeof(unsigned short);  // 16 MiB
    const size_t need = wt_bytes + 1024 * sizeof(float);
    if (ws_size >= need) {
        unsigned short* Wt = (unsigned short*)d_ws;
        float* bias = (float*)((char*)d_ws + wt_bytes);
        hipMemsetAsync(bias, 0, 1024 * sizeof(float), stream);
        prep_kernel<<<512, 256, 0, stream>>>(cc, Wt, bias);
        cheby_gemm<<<512, 256, 0, stream>>>(x, Wt, bias, out);
    } else {
        naive_kernel<<<8192, 256, 0, stream>>>(x, cc, out);
    }
}